// Round 11
// baseline (828.926 us; speedup 1.0000x reference)
//
#include <hip/hip_runtime.h>
#include <hip/hip_fp16.h>
#include <hip/hip_cooperative_groups.h>

namespace cg = cooperative_groups;

#define NNODES 100000
#define NEDGES 1600000
#define NSUB   1000

#define WSHIFT 9                         // 512-node dst windows
#define WIN    512
#define NWIN   ((NNODES + 511) >> 9)     // 196
#define NBLK   256                       // blocks for hist/scatter
#define CHUNK  (NEDGES / NBLK)           // 6250 exact

typedef _Float16 f16x8 __attribute__((ext_vector_type(8)));
typedef float    f32x4 __attribute__((ext_vector_type(4)));

struct Args {
    const float* x; const int* src; const int* dst; const float* ew; const int* subg;
    const float* b1; const float* gn_w; const float* gn_b; const float* gn_ms;
    const float* b2; const float* mW1; const float* mb1; const float* mW2; const float* mb2;
    float* out;
    float* dinv; int* cnt; int* row_ptr; int* flags; unsigned* edges; int2* esw;
    __half* hw; __half* agg; float* stats;
    int* block_counts; int* block_off; int* win_base; int* win_lim; int* cursor;
};

union __align__(16) AShm {
    int hist[NWIN];
    struct { int arr[256]; int red[256]; int base; } off;
    int myoff[NWIN];
    struct { int cnt_l[WIN]; int sc[WIN]; int fill_l[WIN]; float degw[WIN]; } fill;
};
struct BShm { float ls[16][128]; float lq[16][128]; };
struct CShm { int idx[64]; float pl[4][64]; float red[128]; };

// ---------------- phase bodies (shared by coop megas and fallback wrappers) --

__device__ __forceinline__ void phase_hist(const Args& a, AShm& sh) {
    int t = threadIdx.x, b = blockIdx.x;
    if (b >= NBLK) return;
    if (b == 0 && t == 0) *a.cursor = 0;
    if (t < 250) a.flags[a.subg[b * 250 + t]] = 1;   // 256*250 = 64000 exact
    for (int i = t; i < NWIN; i += 256) sh.hist[i] = 0;
    __syncthreads();
    int e0 = b * CHUNK;
    for (int e = e0 + t; e < e0 + CHUNK; e += 256)
        atomicAdd(&sh.hist[a.dst[e] >> WSHIFT], 1);
    __syncthreads();
    for (int i = t; i < NWIN; i += 256) a.block_counts[b * NWIN + i] = sh.hist[i];
    if (b == 0) {
        a.stats[t] = 0.0f; a.stats[t + 256] = 0.0f;
        if (t < 16) a.edges[NEDGES + t] = 0u;        // guard for prop over-read
    }
}

__device__ __forceinline__ void phase_off(const Args& a, AShm& sh) {
    int t = threadIdx.x, w = blockIdx.x;
    if (w >= NWIN) return;
    int own = a.block_counts[t * NWIN + w];
    sh.off.arr[t] = own; sh.off.red[t] = own;
    __syncthreads();
    for (int off = 128; off > 0; off >>= 1) {
        if (t < off) sh.off.red[t] += sh.off.red[t + off];
        __syncthreads();
    }
    if (t == 0) sh.off.base = atomicAdd(a.cursor, sh.off.red[0]);
    for (int off = 1; off < 256; off <<= 1) {
        int v = (t >= off) ? sh.off.arr[t - off] : 0;
        __syncthreads();
        sh.off.arr[t] += v;
        __syncthreads();
    }
    int base = sh.off.base;
    a.block_off[t * NWIN + w] = base + sh.off.arr[t] - own;
    if (t == 0) { a.win_base[w] = base; a.win_lim[w] = base + sh.off.red[0]; }
}

__device__ __forceinline__ void phase_scatter(const Args& a, AShm& sh) {
    int t = threadIdx.x, b = blockIdx.x;
    if (b >= NBLK) return;
    for (int i = t; i < NWIN; i += 256) sh.myoff[i] = a.block_off[b * NWIN + i];
    __syncthreads();
    int e0 = b * CHUNK;
    for (int e = e0 + t; e < e0 + CHUNK; e += 256) {
        int d = a.dst[e];
        int w = d >> WSHIFT;
        int pos = atomicAdd(&sh.myoff[w], 1);
        int dl = d - (w << WSHIFT);
        a.esw[pos] = make_int2((dl << 17) | a.src[e], __float_as_int(a.ew[e]));
    }
}

__device__ __forceinline__ void phase_fill2(const Args& a, AShm& sh) {
    int t = threadIdx.x, w = blockIdx.x;
    if (w >= NWIN) return;
    #pragma unroll
    for (int i = t; i < WIN; i += 256) { sh.fill.cnt_l[i] = 0; sh.fill.fill_l[i] = 0; sh.fill.degw[i] = 0.f; }
    __syncthreads();
    int e0 = a.win_base[w], e1 = a.win_lim[w];
    for (int e = e0 + t; e < e1; e += 256) {
        int2 v = a.esw[e];
        int dl = ((unsigned)v.x) >> 17;
        atomicAdd(&sh.fill.cnt_l[dl], 1);
        atomicAdd(&sh.fill.degw[dl], __int_as_float(v.y));
    }
    __syncthreads();
    sh.fill.sc[t] = sh.fill.cnt_l[t]; sh.fill.sc[t + 256] = sh.fill.cnt_l[t + 256];
    __syncthreads();
    for (int off = 1; off < WIN; off <<= 1) {
        int v0 = (t >= off) ? sh.fill.sc[t - off] : 0;
        int v1 = (t + 256 >= off) ? sh.fill.sc[t + 256 - off] : 0;
        __syncthreads();
        sh.fill.sc[t] += v0; sh.fill.sc[t + 256] += v1;
        __syncthreads();
    }
    sh.fill.sc[t]       = e0 + sh.fill.sc[t]       - sh.fill.cnt_l[t];
    sh.fill.sc[t + 256] = e0 + sh.fill.sc[t + 256] - sh.fill.cnt_l[t + 256];
    __syncthreads();
    for (int e = e0 + t; e < e1; e += 256) {
        int2 v = a.esw[e];
        int dl = ((unsigned)v.x) >> 17;
        int pos = sh.fill.sc[dl] + atomicAdd(&sh.fill.fill_l[dl], 1);
        int wq = __float2int_rn(__int_as_float(v.y) * 32767.0f);
        a.edges[pos] = ((unsigned)wq << 17) | ((unsigned)v.x & 0x1FFFFu);
    }
    __syncthreads();
    #pragma unroll
    for (int i = t; i < WIN; i += 256) {
        int node = (w << WSHIFT) + i;
        if (node < NNODES) {
            a.row_ptr[node] = sh.fill.sc[i];
            a.cnt[node]     = sh.fill.cnt_l[i];
            a.dinv[node]    = rsqrtf(sh.fill.degw[i] + 1.0f);
        }
    }
}

template <bool USE_FLAGS>
__device__ __forceinline__ void phase_prop(const Args& a, const float* bias) {
    int t = threadIdx.x;
    int lane = t & 63, wv = t >> 6;
    int f = lane * 2, feat = f & 63;
    const float qs = 1.0f / 32767.0f;
    float2 bv = *(const float2*)(bias + feat);
    for (int g = blockIdx.x; g < 25000; g += (int)gridDim.x) {
        int n = __builtin_amdgcn_readfirstlane(g * 4 + wv);
        if (USE_FLAGS && a.flags[n] != 1) continue;
        float dv = a.dinv[n];
        float2 self = __half22float2(*(const __half2*)(a.hw + (size_t)n * 128 + f));
        float acc0 = self.x, acc1 = self.y;
        int start = a.row_ptr[n];
        int cn    = a.cnt[n];
        const unsigned* pp = a.edges + start;
        int full = cn & ~15, p = 0;
        for (; p < full; p += 16) {
            unsigned e[16];
            #pragma unroll
            for (int i = 0; i < 16; i++) e[i] = pp[p + i];
            float2 h[16];
            #pragma unroll
            for (int i = 0; i < 16; i++) {
                int s = (int)(e[i] & 0x1FFFFu);
                h[i] = __half22float2(*(const __half2*)(a.hw + (size_t)s * 128 + f));
            }
            #pragma unroll
            for (int i = 0; i < 16; i++) {
                float w = (float)(e[i] >> 17) * qs;
                acc0 += w * h[i].x;
                acc1 += w * h[i].y;
            }
        }
        if (p < cn) {
            unsigned e[16];
            #pragma unroll
            for (int i = 0; i < 16; i++) e[i] = pp[p + i];
            float2 h[16];
            #pragma unroll
            for (int i = 0; i < 16; i++) {
                int s = (int)(e[i] & 0x1FFFFu);
                h[i] = __half22float2(*(const __half2*)(a.hw + (size_t)s * 128 + f));
            }
            #pragma unroll
            for (int i = 0; i < 16; i++) {
                float w = ((p + i) < cn) ? (float)(e[i] >> 17) * qs : 0.0f;
                acc0 += w * h[i].x;
                acc1 += w * h[i].y;
            }
        }
        *(__half2*)(a.agg + (size_t)n * 128 + f) =
            __floats2half2_rn(dv * acc0 + bv.x, dv * acc1 + bv.y);
    }
}

__device__ __forceinline__ void phase_stats(const Args& a, BShm& sh) {
    int t = threadIdx.x;
    int cb = (t & 15) * 8, rg = t >> 4;
    float s[8], q[8];
    #pragma unroll
    for (int i = 0; i < 8; i++) { s[i] = 0.f; q[i] = 0.f; }
    for (int r = blockIdx.x * 16 + rg; r < NNODES; r += (int)gridDim.x * 16) {
        uint4 u = *(const uint4*)(a.agg + (size_t)r * 128 + cb);
        const __half2* h2 = (const __half2*)&u;
        #pragma unroll
        for (int i = 0; i < 4; i++) {
            float2 v = __half22float2(h2[i]);
            s[2*i]   += v.x; q[2*i]   += v.x * v.x;
            s[2*i+1] += v.y; q[2*i+1] += v.y * v.y;
        }
    }
    #pragma unroll
    for (int i = 0; i < 8; i++) { sh.ls[rg][cb + i] = s[i]; sh.lq[rg][cb + i] = q[i]; }
    __syncthreads();
    if (t < 128) {
        float aa = 0.f, b = 0.f;
        #pragma unroll
        for (int g = 0; g < 16; g++) { aa += sh.ls[g][t]; b += sh.lq[g][t]; }
        atomicAdd(&a.stats[t], aa);
        atomicAdd(&a.stats[128 + t], b);
    }
}

__device__ __forceinline__ void phase_head(const Args& a, CShm& sh) {
    int t = threadIdx.x;
    int j = t & 63, grp = t >> 6;
    for (int s = blockIdx.x; s < NSUB; s += (int)gridDim.x) {
        if (t < 64) sh.idx[t] = a.subg[s * 64 + t];
        __syncthreads();
        float acc = 0.f;
        #pragma unroll
        for (int m = grp * 16; m < grp * 16 + 16; m++) {
            int n = sh.idx[m];
            acc += __half2float(a.agg[(size_t)n * 128 + j]) +
                   __half2float(a.agg[(size_t)n * 128 + 64 + j]);
        }
        sh.pl[grp][j] = acc * 0.5f;
        __syncthreads();
        if (t < 64) sh.pl[0][t] = sh.pl[0][t] + sh.pl[1][t] + sh.pl[2][t] + sh.pl[3][t];
        __syncthreads();
        if (t < 128) {
            float h = a.mb1[t];
            #pragma unroll
            for (int k = 0; k < 64; k++) h += sh.pl[0][k] * a.mW1[k * 128 + t];
            h = fmaxf(h, 0.0f);
            sh.red[t] = h * a.mW2[t];
        }
        __syncthreads();
        for (int off = 64; off > 0; off >>= 1) {
            if (t < off) sh.red[t] += sh.red[t + off];
            __syncthreads();
        }
        if (t == 0) a.out[s] = sh.red[0] + a.mb2[0];
        __syncthreads();
    }
}

// ---------------- MFMA GEMM: [200000 x 64] @ [64 x 64] -> fp16, row-scaled --

template <bool TR>
__global__ __launch_bounds__(256) void k_gemm(const void* __restrict__ Xv,
                                              const float* __restrict__ Wg,
                                              const float* __restrict__ dinv,
                                              _Float16* __restrict__ Y,
                                              const float* __restrict__ stats,
                                              const float* __restrict__ gn_w,
                                              const float* __restrict__ gn_b,
                                              const float* __restrict__ gn_ms) {
    __shared__ __align__(16) _Float16 ob[4][16 * 72];
    int t = threadIdx.x;
    int wave = t >> 6, lane = t & 63;
    int m = lane & 15, q = lane >> 4;

    f16x8 bf[2][4];
    #pragma unroll
    for (int kb = 0; kb < 2; kb++)
        #pragma unroll
        for (int nt = 0; nt < 4; nt++)
            #pragma unroll
            for (int j = 0; j < 8; j++)
                bf[kb][nt][j] = (_Float16)Wg[(kb * 32 + q * 8 + j) * 64 + nt * 16 + m];

    float ca[16], cb[16];
    if constexpr (TR) {
        int c = m & 1;
        const float inv_n = 1.0f / (float)NNODES;
        #pragma unroll
        for (int kb = 0; kb < 2; kb++)
            #pragma unroll
            for (int j = 0; j < 8; j++) {
                int k = kb * 32 + q * 8 + j;
                int col = c * 64 + k;
                float mean = stats[col] * inv_n;
                float eh2  = stats[128 + col] * inv_n;
                float ms   = gn_ms[k];
                float mm   = ms * mean;
                float var  = eh2 - 2.0f * mm * mean + mm * mm;
                float A = gn_w[k] * rsqrtf(var + 1e-5f);
                ca[kb * 8 + j] = A;
                cb[kb * 8 + j] = gn_b[k] - A * mm;
            }
    }

    int tile = blockIdx.x * 4 + wave;
    int row0 = tile * 16;

    f16x8 af[2];
    if constexpr (!TR) {
        const float* xp = (const float*)Xv + (size_t)(row0 + m) * 64;
        #pragma unroll
        for (int kb = 0; kb < 2; kb++) {
            float4 u0 = *(const float4*)(xp + kb * 32 + q * 8);
            float4 u1 = *(const float4*)(xp + kb * 32 + q * 8 + 4);
            af[kb][0] = (_Float16)u0.x; af[kb][1] = (_Float16)u0.y;
            af[kb][2] = (_Float16)u0.z; af[kb][3] = (_Float16)u0.w;
            af[kb][4] = (_Float16)u1.x; af[kb][5] = (_Float16)u1.y;
            af[kb][6] = (_Float16)u1.z; af[kb][7] = (_Float16)u1.w;
        }
    } else {
        const _Float16* xp = (const _Float16*)Xv + (size_t)(row0 + m) * 64;
        #pragma unroll
        for (int kb = 0; kb < 2; kb++) {
            f16x8 v = *(const f16x8*)(xp + kb * 32 + q * 8);
            #pragma unroll
            for (int j = 0; j < 8; j++) {
                float f = (float)v[j];
                f = fmaxf(ca[kb * 8 + j] * f + cb[kb * 8 + j], 0.0f);
                af[kb][j] = (_Float16)f;
            }
        }
    }

    f32x4 acc[4];
    #pragma unroll
    for (int nt = 0; nt < 4; nt++) {
        acc[nt] = (f32x4){0.f, 0.f, 0.f, 0.f};
        acc[nt] = __builtin_amdgcn_mfma_f32_16x16x32_f16(af[0], bf[0][nt], acc[nt], 0, 0, 0);
        acc[nt] = __builtin_amdgcn_mfma_f32_16x16x32_f16(af[1], bf[1][nt], acc[nt], 0, 0, 0);
    }

    float dv[4];
    #pragma unroll
    for (int i = 0; i < 4; i++) dv[i] = dinv[(row0 + q * 4 + i) >> 1];

    _Float16* obw = ob[wave];
    #pragma unroll
    for (int nt = 0; nt < 4; nt++)
        #pragma unroll
        for (int i = 0; i < 4; i++)
            obw[(q * 4 + i) * 72 + nt * 16 + m] = (_Float16)(acc[nt][i] * dv[i]);
    __syncthreads();

    _Float16* yp = Y + (size_t)row0 * 64;
    #pragma unroll
    for (int s = 0; s < 2; s++) {
        int c8 = s * 64 + lane;
        int r = c8 >> 3, cg2 = c8 & 7;
        uint4 v = *(const uint4*)(obw + r * 72 + cg2 * 8);
        *(uint4*)(yp + (size_t)r * 64 + cg2 * 8) = v;
    }
}

// ---------------- cooperative megas + fallback wrappers ----------------

__global__ void megaA(Args a) {
    __shared__ AShm sh;
    cg::grid_group g = cg::this_grid();
    phase_hist(a, sh);
    g.sync();
    phase_off(a, sh);
    g.sync();
    phase_scatter(a, sh);
    g.sync();
    phase_fill2(a, sh);
}

__global__ __launch_bounds__(256, 6) void megaB(Args a) {
    __shared__ BShm sh;
    cg::grid_group g = cg::this_grid();
    phase_prop<false>(a, a.b1);
    g.sync();
    phase_stats(a, sh);
}

__global__ __launch_bounds__(256, 6) void megaC(Args a) {
    __shared__ CShm sh;
    cg::grid_group g = cg::this_grid();
    phase_prop<true>(a, a.b2);
    g.sync();
    phase_head(a, sh);
}

__global__ void w_hist(Args a)    { __shared__ AShm sh; phase_hist(a, sh); }
__global__ void w_off(Args a)     { __shared__ AShm sh; phase_off(a, sh); }
__global__ void w_scatter(Args a) { __shared__ AShm sh; phase_scatter(a, sh); }
__global__ void w_fill2(Args a)   { __shared__ AShm sh; phase_fill2(a, sh); }
__global__ __launch_bounds__(256) void w_prop1(Args a) { phase_prop<false>(a, a.b1); }
__global__ __launch_bounds__(256) void w_stats(Args a) { __shared__ BShm sh; phase_stats(a, sh); }
__global__ __launch_bounds__(256) void w_prop2(Args a) { phase_prop<true>(a, a.b2); }
__global__ __launch_bounds__(256) void w_head(Args a)  { __shared__ CShm sh; phase_head(a, sh); }

// ---------------- launcher ----------------

extern "C" void kernel_launch(void* const* d_in, const int* in_sizes, int n_in,
                              void* d_out, int out_size, void* d_ws, size_t ws_size,
                              hipStream_t stream) {
    Args a;
    a.x     = (const float*)d_in[0];
    const int* ei = (const int*)d_in[1];
    a.src   = ei;
    a.dst   = ei + NEDGES;
    a.ew    = (const float*)d_in[2];
    a.subg  = (const int*)d_in[3];
    const float* W1 = (const float*)d_in[4];
    a.b1    = (const float*)d_in[5];
    a.gn_w  = (const float*)d_in[6];
    a.gn_b  = (const float*)d_in[7];
    a.gn_ms = (const float*)d_in[8];
    const float* W2 = (const float*)d_in[9];
    a.b2    = (const float*)d_in[10];
    a.mW1   = (const float*)d_in[11];
    a.mb1   = (const float*)d_in[12];
    a.mW2   = (const float*)d_in[13];
    a.mb2   = (const float*)d_in[14];
    a.out   = (float*)d_out;

    char* w = (char*)d_ws;
    size_t off = 0;
    auto alloc = [&](size_t bytes) {
        void* p = w + off;
        off = (off + bytes + 255) & ~(size_t)255;
        return p;
    };
    a.dinv    = (float*)   alloc((size_t)NNODES * 4);
    a.cnt     = (int*)     alloc((size_t)NNODES * 4);
    a.row_ptr = (int*)     alloc((size_t)NNODES * 4);
    a.flags   = (int*)     alloc((size_t)NNODES * 4);
    a.edges   = (unsigned*)alloc(((size_t)NEDGES + 16) * 4);
    a.esw     = (int2*)    alloc((size_t)NEDGES * 8);
    a.hw      = (__half*)  alloc((size_t)NNODES * 128 * 2);
    a.agg     = (__half*)  alloc((size_t)NNODES * 128 * 2);
    a.stats   = (float*)   alloc(512 * 4);
    a.block_counts = (int*)alloc((size_t)NBLK * NWIN * 4);
    a.block_off    = (int*)alloc((size_t)NBLK * NWIN * 4);
    a.win_base     = (int*)alloc(NWIN * 4);
    a.win_lim      = (int*)alloc(NWIN * 4);
    a.cursor       = (int*)alloc(256);

    // cooperative grid size for megaB/C (clamped by measured occupancy)
    int perCU = 0;
    bool coop = (hipOccupancyMaxActiveBlocksPerMultiprocessor(&perCU, (const void*)megaB, 256, 0)
                 == hipSuccess) && perCU >= 1;
    if (perCU > 6) perCU = 6;
    int NB = (coop ? perCU : 6) * 256;

    void* pa[] = { (void*)&a };

    // preprocessing: hist -> off -> scatter -> fill2
    bool okA = coop &&
        hipLaunchCooperativeKernel((const void*)megaA, dim3(NBLK), dim3(256), pa, 0, stream) == hipSuccess;
    if (!okA) {
        w_hist   <<<NBLK, 256, 0, stream>>>(a);
        w_off    <<<NWIN, 256, 0, stream>>>(a);
        w_scatter<<<NBLK, 256, 0, stream>>>(a);
        w_fill2  <<<NWIN, 256, 0, stream>>>(a);
    }

    // layer 1 GEMM
    k_gemm<false><<<3125, 256, 0, stream>>>(a.x, W1, a.dinv, (_Float16*)a.hw,
                                            nullptr, nullptr, nullptr, nullptr);

    // prop1 + GraphNorm stats
    bool okB = coop &&
        hipLaunchCooperativeKernel((const void*)megaB, dim3(NB), dim3(256), pa, 0, stream) == hipSuccess;
    if (!okB) {
        w_prop1<<<25000, 256, 0, stream>>>(a);
        w_stats<<<512, 256, 0, stream>>>(a);
    }

    // layer 2 GEMM (GraphNorm coef + affine + ReLU fused)
    k_gemm<true><<<3125, 256, 0, stream>>>(a.agg, W2, a.dinv, (_Float16*)a.hw,
                                           a.stats, a.gn_w, a.gn_b, a.gn_ms);

    // prop2 (flag-sparse) + pooling/MLP head
    bool okC = coop &&
        hipLaunchCooperativeKernel((const void*)megaC, dim3(NB), dim3(256), pa, 0, stream) == hipSuccess;
    if (!okC) {
        w_prop2<<<25000, 256, 0, stream>>>(a);
        w_head <<<NSUB, 256, 0, stream>>>(a);
    }
}

// Round 12
// 748.827 us; speedup vs baseline: 1.1070x; 1.1070x over previous
//
#include <hip/hip_runtime.h>
#include <hip/hip_fp16.h>
#include <hip/hip_cooperative_groups.h>

namespace cg = cooperative_groups;

#define NNODES 100000
#define NEDGES 1600000
#define NSUB   1000

#define WSHIFT 9                         // 512-node dst windows
#define WIN    512
#define NWIN   ((NNODES + 511) >> 9)     // 196
#define NBLK   256                       // blocks for hist/scatter
#define CHUNK  (NEDGES / NBLK)           // 6250 exact

typedef _Float16 f16x8 __attribute__((ext_vector_type(8)));
typedef float    f32x4 __attribute__((ext_vector_type(4)));

struct Args {
    const float* x; const int* src; const int* dst; const float* ew; const int* subg;
    const float* b1; const float* gn_w; const float* gn_b; const float* gn_ms;
    const float* b2; const float* mW1; const float* mb1; const float* mW2; const float* mb2;
    float* out;
    float* dinv; int* cnt; int* row_ptr; int* flags; unsigned* edges; int2* esw;
    __half* hw; __half* agg; float* stats;
    int* block_counts; int* block_off; int* win_base; int* win_lim; int* cursor;
};

union __align__(16) AShm {
    int hist[NWIN];
    struct { int arr[256]; int red[256]; int base; } off;
    int myoff[NWIN];
    struct { int cnt_l[WIN]; int sc[WIN]; int fill_l[WIN]; float degw[WIN]; } fill;
};
struct BShm { float ls[16][128]; float lq[16][128]; };
struct CShm { int idx[64]; float pl[4][64]; float red[128]; };

// ---------------- phase bodies (shared by coop megas and fallback wrappers) --

__device__ __forceinline__ void phase_hist(const Args& a, AShm& sh) {
    int t = threadIdx.x, b = blockIdx.x;
    if (b >= NBLK) return;
    if (b == 0 && t == 0) *a.cursor = 0;
    if (t < 250) a.flags[a.subg[b * 250 + t]] = 1;   // 256*250 = 64000 exact
    for (int i = t; i < NWIN; i += 256) sh.hist[i] = 0;
    __syncthreads();
    int e0 = b * CHUNK;
    for (int e = e0 + t; e < e0 + CHUNK; e += 256)
        atomicAdd(&sh.hist[a.dst[e] >> WSHIFT], 1);
    __syncthreads();
    for (int i = t; i < NWIN; i += 256) a.block_counts[b * NWIN + i] = sh.hist[i];
    if (b == 0) {
        a.stats[t] = 0.0f; a.stats[t + 256] = 0.0f;
        if (t < 16) a.edges[NEDGES + t] = 0u;        // guard for prop over-read
    }
}

__device__ __forceinline__ void phase_off(const Args& a, AShm& sh) {
    int t = threadIdx.x, w = blockIdx.x;
    if (w >= NWIN) return;
    int own = a.block_counts[t * NWIN + w];
    sh.off.arr[t] = own; sh.off.red[t] = own;
    __syncthreads();
    for (int off = 128; off > 0; off >>= 1) {
        if (t < off) sh.off.red[t] += sh.off.red[t + off];
        __syncthreads();
    }
    if (t == 0) sh.off.base = atomicAdd(a.cursor, sh.off.red[0]);
    for (int off = 1; off < 256; off <<= 1) {
        int v = (t >= off) ? sh.off.arr[t - off] : 0;
        __syncthreads();
        sh.off.arr[t] += v;
        __syncthreads();
    }
    int base = sh.off.base;
    a.block_off[t * NWIN + w] = base + sh.off.arr[t] - own;
    if (t == 0) { a.win_base[w] = base; a.win_lim[w] = base + sh.off.red[0]; }
}

__device__ __forceinline__ void phase_scatter(const Args& a, AShm& sh) {
    int t = threadIdx.x, b = blockIdx.x;
    if (b >= NBLK) return;
    for (int i = t; i < NWIN; i += 256) sh.myoff[i] = a.block_off[b * NWIN + i];
    __syncthreads();
    int e0 = b * CHUNK;
    for (int e = e0 + t; e < e0 + CHUNK; e += 256) {
        int d = a.dst[e];
        int w = d >> WSHIFT;
        int pos = atomicAdd(&sh.myoff[w], 1);
        int dl = d - (w << WSHIFT);
        a.esw[pos] = make_int2((dl << 17) | a.src[e], __float_as_int(a.ew[e]));
    }
}

__device__ __forceinline__ void phase_fill2(const Args& a, AShm& sh) {
    int t = threadIdx.x, w = blockIdx.x;
    if (w >= NWIN) return;
    #pragma unroll
    for (int i = t; i < WIN; i += 256) { sh.fill.cnt_l[i] = 0; sh.fill.fill_l[i] = 0; sh.fill.degw[i] = 0.f; }
    __syncthreads();
    int e0 = a.win_base[w], e1 = a.win_lim[w];
    for (int e = e0 + t; e < e1; e += 256) {
        int2 v = a.esw[e];
        int dl = ((unsigned)v.x) >> 17;
        atomicAdd(&sh.fill.cnt_l[dl], 1);
        atomicAdd(&sh.fill.degw[dl], __int_as_float(v.y));
    }
    __syncthreads();
    sh.fill.sc[t] = sh.fill.cnt_l[t]; sh.fill.sc[t + 256] = sh.fill.cnt_l[t + 256];
    __syncthreads();
    for (int off = 1; off < WIN; off <<= 1) {
        int v0 = (t >= off) ? sh.fill.sc[t - off] : 0;
        int v1 = (t + 256 >= off) ? sh.fill.sc[t + 256 - off] : 0;
        __syncthreads();
        sh.fill.sc[t] += v0; sh.fill.sc[t + 256] += v1;
        __syncthreads();
    }
    sh.fill.sc[t]       = e0 + sh.fill.sc[t]       - sh.fill.cnt_l[t];
    sh.fill.sc[t + 256] = e0 + sh.fill.sc[t + 256] - sh.fill.cnt_l[t + 256];
    __syncthreads();
    for (int e = e0 + t; e < e1; e += 256) {
        int2 v = a.esw[e];
        int dl = ((unsigned)v.x) >> 17;
        int pos = sh.fill.sc[dl] + atomicAdd(&sh.fill.fill_l[dl], 1);
        int wq = __float2int_rn(__int_as_float(v.y) * 32767.0f);
        a.edges[pos] = ((unsigned)wq << 17) | ((unsigned)v.x & 0x1FFFFu);
    }
    __syncthreads();
    #pragma unroll
    for (int i = t; i < WIN; i += 256) {
        int node = (w << WSHIFT) + i;
        if (node < NNODES) {
            a.row_ptr[node] = sh.fill.sc[i];
            a.cnt[node]     = sh.fill.cnt_l[i];
            a.dinv[node]    = rsqrtf(sh.fill.degw[i] + 1.0f);
        }
    }
}

template <bool USE_FLAGS>
__device__ __forceinline__ void phase_prop(const Args& a, const float* bias) {
    int t = threadIdx.x;
    int lane = t & 63, wv = t >> 6;
    int f = lane * 2, feat = f & 63;
    const float qs = 1.0f / 32767.0f;
    float2 bv = *(const float2*)(bias + feat);
    for (int g = blockIdx.x; g < 25000; g += (int)gridDim.x) {
        int n = __builtin_amdgcn_readfirstlane(g * 4 + wv);
        if (USE_FLAGS && a.flags[n] != 1) continue;
        float dv = a.dinv[n];
        float2 self = __half22float2(*(const __half2*)(a.hw + (size_t)n * 128 + f));
        float acc0 = self.x, acc1 = self.y;
        int start = a.row_ptr[n];
        int cn    = a.cnt[n];
        const unsigned* pp = a.edges + start;
        int full = cn & ~15, p = 0;
        for (; p < full; p += 16) {
            unsigned e[16];
            #pragma unroll
            for (int i = 0; i < 16; i++) e[i] = pp[p + i];
            float2 h[16];
            #pragma unroll
            for (int i = 0; i < 16; i++) {
                int s = (int)(e[i] & 0x1FFFFu);
                h[i] = __half22float2(*(const __half2*)(a.hw + (size_t)s * 128 + f));
            }
            #pragma unroll
            for (int i = 0; i < 16; i++) {
                float w = (float)(e[i] >> 17) * qs;
                acc0 += w * h[i].x;
                acc1 += w * h[i].y;
            }
        }
        if (p < cn) {
            unsigned e[16];
            #pragma unroll
            for (int i = 0; i < 16; i++) e[i] = pp[p + i];
            float2 h[16];
            #pragma unroll
            for (int i = 0; i < 16; i++) {
                int s = (int)(e[i] & 0x1FFFFu);
                h[i] = __half22float2(*(const __half2*)(a.hw + (size_t)s * 128 + f));
            }
            #pragma unroll
            for (int i = 0; i < 16; i++) {
                float w = ((p + i) < cn) ? (float)(e[i] >> 17) * qs : 0.0f;
                acc0 += w * h[i].x;
                acc1 += w * h[i].y;
            }
        }
        *(__half2*)(a.agg + (size_t)n * 128 + f) =
            __floats2half2_rn(dv * acc0 + bv.x, dv * acc1 + bv.y);
    }
}

__device__ __forceinline__ void phase_stats(const Args& a, BShm& sh) {
    int t = threadIdx.x;
    int cb = (t & 15) * 8, rg = t >> 4;
    float s[8], q[8];
    #pragma unroll
    for (int i = 0; i < 8; i++) { s[i] = 0.f; q[i] = 0.f; }
    for (int r = blockIdx.x * 16 + rg; r < NNODES; r += (int)gridDim.x * 16) {
        uint4 u = *(const uint4*)(a.agg + (size_t)r * 128 + cb);
        const __half2* h2 = (const __half2*)&u;
        #pragma unroll
        for (int i = 0; i < 4; i++) {
            float2 v = __half22float2(h2[i]);
            s[2*i]   += v.x; q[2*i]   += v.x * v.x;
            s[2*i+1] += v.y; q[2*i+1] += v.y * v.y;
        }
    }
    #pragma unroll
    for (int i = 0; i < 8; i++) { sh.ls[rg][cb + i] = s[i]; sh.lq[rg][cb + i] = q[i]; }
    __syncthreads();
    if (t < 128) {
        float aa = 0.f, b = 0.f;
        #pragma unroll
        for (int g = 0; g < 16; g++) { aa += sh.ls[g][t]; b += sh.lq[g][t]; }
        atomicAdd(&a.stats[t], aa);
        atomicAdd(&a.stats[128 + t], b);
    }
}

__device__ __forceinline__ void phase_head(const Args& a, CShm& sh) {
    int t = threadIdx.x;
    int j = t & 63, grp = t >> 6;
    for (int s = blockIdx.x; s < NSUB; s += (int)gridDim.x) {
        if (t < 64) sh.idx[t] = a.subg[s * 64 + t];
        __syncthreads();
        float acc = 0.f;
        #pragma unroll
        for (int m = grp * 16; m < grp * 16 + 16; m++) {
            int n = sh.idx[m];
            acc += __half2float(a.agg[(size_t)n * 128 + j]) +
                   __half2float(a.agg[(size_t)n * 128 + 64 + j]);
        }
        sh.pl[grp][j] = acc * 0.5f;
        __syncthreads();
        if (t < 64) sh.pl[0][t] = sh.pl[0][t] + sh.pl[1][t] + sh.pl[2][t] + sh.pl[3][t];
        __syncthreads();
        if (t < 128) {
            float h = a.mb1[t];
            #pragma unroll
            for (int k = 0; k < 64; k++) h += sh.pl[0][k] * a.mW1[k * 128 + t];
            h = fmaxf(h, 0.0f);
            sh.red[t] = h * a.mW2[t];
        }
        __syncthreads();
        for (int off = 64; off > 0; off >>= 1) {
            if (t < off) sh.red[t] += sh.red[t + off];
            __syncthreads();
        }
        if (t == 0) a.out[s] = sh.red[0] + a.mb2[0];
        __syncthreads();
    }
}

// ---------------- MFMA GEMM: [200000 x 64] @ [64 x 64] -> fp16, row-scaled --

template <bool TR>
__global__ __launch_bounds__(256) void k_gemm(const void* __restrict__ Xv,
                                              const float* __restrict__ Wg,
                                              const float* __restrict__ dinv,
                                              _Float16* __restrict__ Y,
                                              const float* __restrict__ stats,
                                              const float* __restrict__ gn_w,
                                              const float* __restrict__ gn_b,
                                              const float* __restrict__ gn_ms) {
    __shared__ __align__(16) _Float16 ob[4][16 * 72];
    int t = threadIdx.x;
    int wave = t >> 6, lane = t & 63;
    int m = lane & 15, q = lane >> 4;

    f16x8 bf[2][4];
    #pragma unroll
    for (int kb = 0; kb < 2; kb++)
        #pragma unroll
        for (int nt = 0; nt < 4; nt++)
            #pragma unroll
            for (int j = 0; j < 8; j++)
                bf[kb][nt][j] = (_Float16)Wg[(kb * 32 + q * 8 + j) * 64 + nt * 16 + m];

    float ca[16], cb[16];
    if constexpr (TR) {
        int c = m & 1;
        const float inv_n = 1.0f / (float)NNODES;
        #pragma unroll
        for (int kb = 0; kb < 2; kb++)
            #pragma unroll
            for (int j = 0; j < 8; j++) {
                int k = kb * 32 + q * 8 + j;
                int col = c * 64 + k;
                float mean = stats[col] * inv_n;
                float eh2  = stats[128 + col] * inv_n;
                float ms   = gn_ms[k];
                float mm   = ms * mean;
                float var  = eh2 - 2.0f * mm * mean + mm * mm;
                float A = gn_w[k] * rsqrtf(var + 1e-5f);
                ca[kb * 8 + j] = A;
                cb[kb * 8 + j] = gn_b[k] - A * mm;
            }
    }

    int tile = blockIdx.x * 4 + wave;
    int row0 = tile * 16;

    f16x8 af[2];
    if constexpr (!TR) {
        const float* xp = (const float*)Xv + (size_t)(row0 + m) * 64;
        #pragma unroll
        for (int kb = 0; kb < 2; kb++) {
            float4 u0 = *(const float4*)(xp + kb * 32 + q * 8);
            float4 u1 = *(const float4*)(xp + kb * 32 + q * 8 + 4);
            af[kb][0] = (_Float16)u0.x; af[kb][1] = (_Float16)u0.y;
            af[kb][2] = (_Float16)u0.z; af[kb][3] = (_Float16)u0.w;
            af[kb][4] = (_Float16)u1.x; af[kb][5] = (_Float16)u1.y;
            af[kb][6] = (_Float16)u1.z; af[kb][7] = (_Float16)u1.w;
        }
    } else {
        const _Float16* xp = (const _Float16*)Xv + (size_t)(row0 + m) * 64;
        #pragma unroll
        for (int kb = 0; kb < 2; kb++) {
            f16x8 v = *(const f16x8*)(xp + kb * 32 + q * 8);
            #pragma unroll
            for (int j = 0; j < 8; j++) {
                float f = (float)v[j];
                f = fmaxf(ca[kb * 8 + j] * f + cb[kb * 8 + j], 0.0f);
                af[kb][j] = (_Float16)f;
            }
        }
    }

    f32x4 acc[4];
    #pragma unroll
    for (int nt = 0; nt < 4; nt++) {
        acc[nt] = (f32x4){0.f, 0.f, 0.f, 0.f};
        acc[nt] = __builtin_amdgcn_mfma_f32_16x16x32_f16(af[0], bf[0][nt], acc[nt], 0, 0, 0);
        acc[nt] = __builtin_amdgcn_mfma_f32_16x16x32_f16(af[1], bf[1][nt], acc[nt], 0, 0, 0);
    }

    float dv[4];
    #pragma unroll
    for (int i = 0; i < 4; i++) dv[i] = dinv[(row0 + q * 4 + i) >> 1];

    _Float16* obw = ob[wave];
    #pragma unroll
    for (int nt = 0; nt < 4; nt++)
        #pragma unroll
        for (int i = 0; i < 4; i++)
            obw[(q * 4 + i) * 72 + nt * 16 + m] = (_Float16)(acc[nt][i] * dv[i]);
    __syncthreads();

    _Float16* yp = Y + (size_t)row0 * 64;
    #pragma unroll
    for (int s = 0; s < 2; s++) {
        int c8 = s * 64 + lane;
        int r = c8 >> 3, cg2 = c8 & 7;
        uint4 v = *(const uint4*)(obw + r * 72 + cg2 * 8);
        *(uint4*)(yp + (size_t)r * 64 + cg2 * 8) = v;
    }
}

// ---------------- cooperative megas + fallback wrappers ----------------
// NOTE: no min-waves clause in __launch_bounds__ — r11 showed that (256,6)
// capped VGPRs at 32 and serialized the 16-deep gather pipeline (3.9 TB/s ->
// 874 GB/s). Let the allocator take what the batch needs; size the coop grid
// from the occupancy query instead.

__global__ void megaA(Args a) {
    __shared__ AShm sh;
    cg::grid_group g = cg::this_grid();
    phase_hist(a, sh);
    g.sync();
    phase_off(a, sh);
    g.sync();
    phase_scatter(a, sh);
    g.sync();
    phase_fill2(a, sh);
}

__global__ __launch_bounds__(256) void megaB(Args a) {
    __shared__ BShm sh;
    cg::grid_group g = cg::this_grid();
    phase_prop<false>(a, a.b1);
    g.sync();
    phase_stats(a, sh);
}

__global__ __launch_bounds__(256) void megaC(Args a) {
    __shared__ CShm sh;
    cg::grid_group g = cg::this_grid();
    phase_prop<true>(a, a.b2);
    g.sync();
    phase_head(a, sh);
}

__global__ void w_hist(Args a)    { __shared__ AShm sh; phase_hist(a, sh); }
__global__ void w_off(Args a)     { __shared__ AShm sh; phase_off(a, sh); }
__global__ void w_scatter(Args a) { __shared__ AShm sh; phase_scatter(a, sh); }
__global__ void w_fill2(Args a)   { __shared__ AShm sh; phase_fill2(a, sh); }
__global__ __launch_bounds__(256) void w_prop1(Args a) { phase_prop<false>(a, a.b1); }
__global__ __launch_bounds__(256) void w_stats(Args a) { __shared__ BShm sh; phase_stats(a, sh); }
__global__ __launch_bounds__(256) void w_prop2(Args a) { phase_prop<true>(a, a.b2); }
__global__ __launch_bounds__(256) void w_head(Args a)  { __shared__ CShm sh; phase_head(a, sh); }

// ---------------- launcher ----------------

extern "C" void kernel_launch(void* const* d_in, const int* in_sizes, int n_in,
                              void* d_out, int out_size, void* d_ws, size_t ws_size,
                              hipStream_t stream) {
    Args a;
    a.x     = (const float*)d_in[0];
    const int* ei = (const int*)d_in[1];
    a.src   = ei;
    a.dst   = ei + NEDGES;
    a.ew    = (const float*)d_in[2];
    a.subg  = (const int*)d_in[3];
    const float* W1 = (const float*)d_in[4];
    a.b1    = (const float*)d_in[5];
    a.gn_w  = (const float*)d_in[6];
    a.gn_b  = (const float*)d_in[7];
    a.gn_ms = (const float*)d_in[8];
    const float* W2 = (const float*)d_in[9];
    a.b2    = (const float*)d_in[10];
    a.mW1   = (const float*)d_in[11];
    a.mb1   = (const float*)d_in[12];
    a.mW2   = (const float*)d_in[13];
    a.mb2   = (const float*)d_in[14];
    a.out   = (float*)d_out;

    char* w = (char*)d_ws;
    size_t off = 0;
    auto alloc = [&](size_t bytes) {
        void* p = w + off;
        off = (off + bytes + 255) & ~(size_t)255;
        return p;
    };
    a.dinv    = (float*)   alloc((size_t)NNODES * 4);
    a.cnt     = (int*)     alloc((size_t)NNODES * 4);
    a.row_ptr = (int*)     alloc((size_t)NNODES * 4);
    a.flags   = (int*)     alloc((size_t)NNODES * 4);
    a.edges   = (unsigned*)alloc(((size_t)NEDGES + 16) * 4);
    a.esw     = (int2*)    alloc((size_t)NEDGES * 8);
    a.hw      = (__half*)  alloc((size_t)NNODES * 128 * 2);
    a.agg     = (__half*)  alloc((size_t)NNODES * 128 * 2);
    a.stats   = (float*)   alloc(512 * 4);
    a.block_counts = (int*)alloc((size_t)NBLK * NWIN * 4);
    a.block_off    = (int*)alloc((size_t)NBLK * NWIN * 4);
    a.win_base     = (int*)alloc(NWIN * 4);
    a.win_lim      = (int*)alloc(NWIN * 4);
    a.cursor       = (int*)alloc(256);

    // per-kernel cooperative grid sizes from occupancy (no VGPR cap imposed)
    int perB = 0, perC = 0;
    bool coop =
        hipOccupancyMaxActiveBlocksPerMultiprocessor(&perB, (const void*)megaB, 256, 0) == hipSuccess &&
        hipOccupancyMaxActiveBlocksPerMultiprocessor(&perC, (const void*)megaC, 256, 0) == hipSuccess &&
        perB >= 1 && perC >= 1;
    int NBb = perB * 256;
    int NBc = perC * 256;

    void* pa[] = { (void*)&a };

    // preprocessing: hist -> off -> scatter -> fill2
    bool okA = coop &&
        hipLaunchCooperativeKernel((const void*)megaA, dim3(NBLK), dim3(256), pa, 0, stream) == hipSuccess;
    if (!okA) {
        w_hist   <<<NBLK, 256, 0, stream>>>(a);
        w_off    <<<NWIN, 256, 0, stream>>>(a);
        w_scatter<<<NBLK, 256, 0, stream>>>(a);
        w_fill2  <<<NWIN, 256, 0, stream>>>(a);
    }

    // layer 1 GEMM
    k_gemm<false><<<3125, 256, 0, stream>>>(a.x, W1, a.dinv, (_Float16*)a.hw,
                                            nullptr, nullptr, nullptr, nullptr);

    // prop1 + GraphNorm stats
    bool okB = coop &&
        hipLaunchCooperativeKernel((const void*)megaB, dim3(NBb), dim3(256), pa, 0, stream) == hipSuccess;
    if (!okB) {
        w_prop1<<<25000, 256, 0, stream>>>(a);
        w_stats<<<512, 256, 0, stream>>>(a);
    }

    // layer 2 GEMM (GraphNorm coef + affine + ReLU fused)
    k_gemm<true><<<3125, 256, 0, stream>>>(a.agg, W2, a.dinv, (_Float16*)a.hw,
                                           a.stats, a.gn_w, a.gn_b, a.gn_ms);

    // prop2 (flag-sparse) + pooling/MLP head
    bool okC = coop &&
        hipLaunchCooperativeKernel((const void*)megaC, dim3(NBc), dim3(256), pa, 0, stream) == hipSuccess;
    if (!okC) {
        w_prop2<<<25000, 256, 0, stream>>>(a);
        w_head <<<NSUB, 256, 0, stream>>>(a);
    }
}

// Round 13
// 330.392 us; speedup vs baseline: 2.5089x; 2.2665x over previous
//
#include <hip/hip_runtime.h>
#include <hip/hip_fp16.h>

// NOTE (r11/r12 post-mortem): cooperative mega-kernel fusion of
// prop+stats / prop+head regressed 2-6x. The fused grid-stride bodies compile
// to a register-minimized schedule (VGPR 32) that serializes the 16-deep
// gather pipeline (3.9 TB/s -> 0.6-0.9 TB/s), independent of the
// __launch_bounds__ min-waves clause. Keep props as standalone kernels.

#define NNODES 100000
#define NEDGES 1600000
#define NSUB   1000
#define MSUB   64
#define MHID   128

#define WSHIFT 9                         // 512-node dst windows
#define WIN    512
#define NWIN   ((NNODES + 511) >> 9)     // 196
#define NBLK   256                       // blocks for hist/scatter
#define CHUNK  (NEDGES / NBLK)           // 6250 exact

typedef _Float16 f16x8 __attribute__((ext_vector_type(8)));
typedef float    f32x4 __attribute__((ext_vector_type(4)));

// ---------------- edge binning: counting sort by dst window ----------------
// Also marks head-needed nodes (flags[subg[i]] = 1) — layer-2 aggregation is
// only consumed through subG pooling, so prop2 can skip unmarked nodes.

__global__ __launch_bounds__(256) void k_hist(const int* __restrict__ dst,
                                              int* __restrict__ block_counts,
                                              int* __restrict__ cursor,
                                              const int* __restrict__ subg,
                                              int* __restrict__ flags) {
    __shared__ int hist[NWIN];
    int t = threadIdx.x, b = blockIdx.x;
    if (b == 0 && t == 0) *cursor = 0;
    if (t < 250) flags[subg[b * 250 + t]] = 1;    // 256*250 = 64000 exact
    for (int i = t; i < NWIN; i += 256) hist[i] = 0;
    __syncthreads();
    int e0 = b * CHUNK;
    for (int e = e0 + t; e < e0 + CHUNK; e += 256)
        atomicAdd(&hist[dst[e] >> WSHIFT], 1);
    __syncthreads();
    for (int i = t; i < NWIN; i += 256) block_counts[b * NWIN + i] = hist[i];
}

// one block per window: total (reduce) -> base (atomic cursor; window order in
// the CSR is arbitrary but contiguous) -> per-block offsets (scan). Also zeroes
// stats and writes the prop guard entries (block 0).
__global__ __launch_bounds__(256) void k_off(const int* __restrict__ block_counts,
                                             int* __restrict__ cursor,
                                             int* __restrict__ win_base,
                                             int* __restrict__ win_lim,
                                             int* __restrict__ block_off,
                                             float* __restrict__ stats,
                                             unsigned* __restrict__ edges) {
    __shared__ int arr[256];
    __shared__ int red[256];
    __shared__ int base_s;
    int t = threadIdx.x, w = blockIdx.x;
    int own = block_counts[t * NWIN + w];
    arr[t] = own; red[t] = own;
    __syncthreads();
    for (int off = 128; off > 0; off >>= 1) {
        if (t < off) red[t] += red[t + off];
        __syncthreads();
    }
    if (t == 0) base_s = atomicAdd(cursor, red[0]);
    for (int off = 1; off < 256; off <<= 1) {
        int v = (t >= off) ? arr[t - off] : 0;
        __syncthreads();
        arr[t] += v;
        __syncthreads();
    }
    int base = base_s;
    block_off[t * NWIN + w] = base + arr[t] - own;
    if (t == 0) { win_base[w] = base; win_lim[w] = base + red[0]; }
    if (w == 0) {
        stats[t] = 0.0f; stats[t + 256] = 0.0f;
        if (t < 16) edges[NEDGES + t] = 0u;
    }
}

__global__ __launch_bounds__(256) void k_scatter(const int* __restrict__ src,
                                                 const int* __restrict__ dst,
                                                 const float* __restrict__ ew,
                                                 const int* __restrict__ block_off,
                                                 int2* __restrict__ esw) {
    __shared__ int myoff[NWIN];
    int t = threadIdx.x, b = blockIdx.x;
    for (int i = t; i < NWIN; i += 256) myoff[i] = block_off[b * NWIN + i];
    __syncthreads();
    int e0 = b * CHUNK;
    for (int e = e0 + t; e < e0 + CHUNK; e += 256) {
        int d = dst[e];
        int w = d >> WSHIFT;
        int pos = atomicAdd(&myoff[w], 1);
        int dl = d - (w << WSHIFT);
        esw[pos] = make_int2((dl << 17) | src[e], __float_as_int(ew[e]));
    }
}

// one block per window: dense CSR (4 B packed entries: wq15<<17 | src17) +
// raw-weight degree sums -> dinv.
__global__ __launch_bounds__(256) void k_fill2(const int* __restrict__ win_base,
                                               const int* __restrict__ win_lim,
                                               const int2* __restrict__ esw,
                                               unsigned* __restrict__ edges,
                                               int* __restrict__ row_ptr,
                                               int* __restrict__ cnt,
                                               float* __restrict__ dinv) {
    __shared__ int   cnt_l[WIN];
    __shared__ int   sc[WIN];
    __shared__ int   fill_l[WIN];
    __shared__ float degw[WIN];
    int t = threadIdx.x, w = blockIdx.x;
    #pragma unroll
    for (int i = t; i < WIN; i += 256) { cnt_l[i] = 0; fill_l[i] = 0; degw[i] = 0.f; }
    __syncthreads();
    int e0 = win_base[w], e1 = win_lim[w];
    for (int e = e0 + t; e < e1; e += 256) {
        int2 v = esw[e];
        int dl = ((unsigned)v.x) >> 17;
        atomicAdd(&cnt_l[dl], 1);
        atomicAdd(&degw[dl], __int_as_float(v.y));
    }
    __syncthreads();
    sc[t] = cnt_l[t]; sc[t + 256] = cnt_l[t + 256];
    __syncthreads();
    for (int off = 1; off < WIN; off <<= 1) {
        int v0 = (t >= off) ? sc[t - off] : 0;
        int v1 = (t + 256 >= off) ? sc[t + 256 - off] : 0;
        __syncthreads();
        sc[t] += v0; sc[t + 256] += v1;
        __syncthreads();
    }
    sc[t]       = e0 + sc[t]       - cnt_l[t];
    sc[t + 256] = e0 + sc[t + 256] - cnt_l[t + 256];
    __syncthreads();
    for (int e = e0 + t; e < e1; e += 256) {
        int2 v = esw[e];
        int dl = ((unsigned)v.x) >> 17;
        int pos = sc[dl] + atomicAdd(&fill_l[dl], 1);
        int wq = __float2int_rn(__int_as_float(v.y) * 32767.0f);
        edges[pos] = ((unsigned)wq << 17) | ((unsigned)v.x & 0x1FFFFu);
    }
    __syncthreads();
    #pragma unroll
    for (int i = t; i < WIN; i += 256) {
        int node = (w << WSHIFT) + i;
        if (node < NNODES) {
            row_ptr[node] = sc[i];
            cnt[node]     = cnt_l[i];
            dinv[node]    = rsqrtf(degw[i] + 1.0f);
        }
    }
}

// ---------------- MFMA GEMM: [200000 x 64] @ [64 x 64] -> fp16, row-scaled --
// Wave = one 16x64 tile, K=64: 8 x mfma_f32_16x16x32_f16. TR=true computes
// GraphNorm coefs per-thread from stats (k_coef folded in).

template <bool TR>
__global__ __launch_bounds__(256) void k_gemm(const void* __restrict__ Xv,
                                              const float* __restrict__ Wg,
                                              const float* __restrict__ dinv,
                                              _Float16* __restrict__ Y,
                                              const float* __restrict__ stats,
                                              const float* __restrict__ gn_w,
                                              const float* __restrict__ gn_b,
                                              const float* __restrict__ gn_ms) {
    __shared__ __align__(16) _Float16 ob[4][16 * 72];   // per-wave 16x64 (+pad 8)
    int t = threadIdx.x;
    int wave = t >> 6, lane = t & 63;
    int m = lane & 15, q = lane >> 4;

    // B fragments: B[k = kb*32 + q*8 + j][n = nt*16 + m]
    f16x8 bf[2][4];
    #pragma unroll
    for (int kb = 0; kb < 2; kb++)
        #pragma unroll
        for (int nt = 0; nt < 4; nt++)
            #pragma unroll
            for (int j = 0; j < 8; j++)
                bf[kb][nt][j] = (_Float16)Wg[(kb * 32 + q * 8 + j) * 64 + nt * 16 + m];

    float ca[16], cb[16];
    if constexpr (TR) {
        int c = m & 1;     // row = n*2+c -> channel = m & 1
        const float inv_n = 1.0f / (float)NNODES;
        #pragma unroll
        for (int kb = 0; kb < 2; kb++)
            #pragma unroll
            for (int j = 0; j < 8; j++) {
                int k = kb * 32 + q * 8 + j;
                int col = c * 64 + k;
                float mean = stats[col] * inv_n;
                float eh2  = stats[128 + col] * inv_n;
                float ms   = gn_ms[k];
                float mm   = ms * mean;
                float var  = eh2 - 2.0f * mm * mean + mm * mm;
                float A = gn_w[k] * rsqrtf(var + 1e-5f);
                ca[kb * 8 + j] = A;
                cb[kb * 8 + j] = gn_b[k] - A * mm;
            }
    }

    int tile = blockIdx.x * 4 + wave;
    int row0 = tile * 16;

    f16x8 af[2];
    if constexpr (!TR) {
        const float* xp = (const float*)Xv + (size_t)(row0 + m) * 64;
        #pragma unroll
        for (int kb = 0; kb < 2; kb++) {
            float4 u0 = *(const float4*)(xp + kb * 32 + q * 8);
            float4 u1 = *(const float4*)(xp + kb * 32 + q * 8 + 4);
            af[kb][0] = (_Float16)u0.x; af[kb][1] = (_Float16)u0.y;
            af[kb][2] = (_Float16)u0.z; af[kb][3] = (_Float16)u0.w;
            af[kb][4] = (_Float16)u1.x; af[kb][5] = (_Float16)u1.y;
            af[kb][6] = (_Float16)u1.z; af[kb][7] = (_Float16)u1.w;
        }
    } else {
        const _Float16* xp = (const _Float16*)Xv + (size_t)(row0 + m) * 64;
        #pragma unroll
        for (int kb = 0; kb < 2; kb++) {
            f16x8 v = *(const f16x8*)(xp + kb * 32 + q * 8);
            #pragma unroll
            for (int j = 0; j < 8; j++) {
                float f = (float)v[j];
                f = fmaxf(ca[kb * 8 + j] * f + cb[kb * 8 + j], 0.0f);
                af[kb][j] = (_Float16)f;
            }
        }
    }

    f32x4 acc[4];
    #pragma unroll
    for (int nt = 0; nt < 4; nt++) {
        acc[nt] = (f32x4){0.f, 0.f, 0.f, 0.f};
        acc[nt] = __builtin_amdgcn_mfma_f32_16x16x32_f16(af[0], bf[0][nt], acc[nt], 0, 0, 0);
        acc[nt] = __builtin_amdgcn_mfma_f32_16x16x32_f16(af[1], bf[1][nt], acc[nt], 0, 0, 0);
    }

    float dv[4];
    #pragma unroll
    for (int i = 0; i < 4; i++) dv[i] = dinv[(row0 + q * 4 + i) >> 1];

    _Float16* obw = ob[wave];
    #pragma unroll
    for (int nt = 0; nt < 4; nt++)
        #pragma unroll
        for (int i = 0; i < 4; i++)
            obw[(q * 4 + i) * 72 + nt * 16 + m] = (_Float16)(acc[nt][i] * dv[i]);
    __syncthreads();

    _Float16* yp = Y + (size_t)row0 * 64;
    #pragma unroll
    for (int s = 0; s < 2; s++) {
        int c8 = s * 64 + lane;
        int r = c8 >> 3, cg2 = c8 & 7;
        uint4 v = *(const uint4*)(obw + r * 72 + cg2 * 8);
        *(uint4*)(yp + (size_t)r * 64 + cg2 * 8) = v;
    }
}

// ---------------- pull-style GCN aggregation (fp16, packed dense CSR) ------
// agg[n] = dinv[n] * (hw'[n] + sum_e ew_e * hw'[src_e]) + bias
// USE_FLAGS (layer 2): skip nodes not referenced by any subgraph.

template <bool USE_FLAGS>
__global__ __launch_bounds__(256) void k_prop(const __half* __restrict__ hw,
                                              const float* __restrict__ bias,
                                              const float* __restrict__ dinv,
                                              const int* __restrict__ row_ptr,
                                              const int* __restrict__ cnt,
                                              const unsigned* __restrict__ edges,
                                              const int* __restrict__ flags,
                                              __half* __restrict__ agg) {
    int t = threadIdx.x;
    int lane = t & 63;
    int n = __builtin_amdgcn_readfirstlane(blockIdx.x * 4 + (t >> 6));
    if (n >= NNODES) return;
    if constexpr (USE_FLAGS) { if (flags[n] != 1) return; }

    int f = lane * 2;            // flat half-offset in [0,128), even
    int feat = f & 63;
    const float qs = 1.0f / 32767.0f;

    float2 bv = *(const float2*)(bias + feat);
    float dv = dinv[n];
    float2 self = __half22float2(*(const __half2*)(hw + (size_t)n * 128 + f));
    float acc0 = self.x;
    float acc1 = self.y;

    int start = row_ptr[n];
    int cn    = cnt[n];
    const unsigned* pp = edges + start;

    int full = cn & ~15;
    int p = 0;
    for (; p < full; p += 16) {
        unsigned e[16];
        #pragma unroll
        for (int i = 0; i < 16; i++) e[i] = pp[p + i];
        float2 h[16];
        #pragma unroll
        for (int i = 0; i < 16; i++) {
            int s = (int)(e[i] & 0x1FFFFu);
            h[i] = __half22float2(*(const __half2*)(hw + (size_t)s * 128 + f));
        }
        #pragma unroll
        for (int i = 0; i < 16; i++) {
            float w = (float)(e[i] >> 17) * qs;
            acc0 += w * h[i].x;
            acc1 += w * h[i].y;
        }
    }
    if (p < cn) {
        unsigned e[16];
        #pragma unroll
        for (int i = 0; i < 16; i++) e[i] = pp[p + i];
        float2 h[16];
        #pragma unroll
        for (int i = 0; i < 16; i++) {
            int s = (int)(e[i] & 0x1FFFFu);
            h[i] = __half22float2(*(const __half2*)(hw + (size_t)s * 128 + f));
        }
        #pragma unroll
        for (int i = 0; i < 16; i++) {
            float w = ((p + i) < cn) ? (float)(e[i] >> 17) * qs : 0.0f;
            acc0 += w * h[i].x;
            acc1 += w * h[i].y;
        }
    }

    *(__half2*)(agg + (size_t)n * 128 + f) =
        __floats2half2_rn(dv * acc0 + bv.x, dv * acc1 + bv.y);
}

// ---------------- GraphNorm stats (sum, sumsq per column) ----------------

__global__ __launch_bounds__(256) void k_stats(const __half* __restrict__ agg,
                                               float* __restrict__ stats) {
    __shared__ float ls[16][128];
    __shared__ float lq[16][128];
    int t = threadIdx.x;
    int cb = (t & 15) * 8;
    int rg = t >> 4;
    float s[8], q[8];
    #pragma unroll
    for (int i = 0; i < 8; i++) { s[i] = 0.f; q[i] = 0.f; }
    for (int r = blockIdx.x * 16 + rg; r < NNODES; r += gridDim.x * 16) {
        uint4 u = *(const uint4*)(agg + (size_t)r * 128 + cb);
        const __half2* h2 = (const __half2*)&u;
        #pragma unroll
        for (int i = 0; i < 4; i++) {
            float2 v = __half22float2(h2[i]);
            s[2*i]   += v.x; q[2*i]   += v.x * v.x;
            s[2*i+1] += v.y; q[2*i+1] += v.y * v.y;
        }
    }
    #pragma unroll
    for (int i = 0; i < 8; i++) { ls[rg][cb + i] = s[i]; lq[rg][cb + i] = q[i]; }
    __syncthreads();
    if (t < 128) {
        float a = 0.f, b = 0.f;
        #pragma unroll
        for (int g = 0; g < 16; g++) { a += ls[g][t]; b += lq[g][t]; }
        atomicAdd(&stats[t], a);
        atomicAdd(&stats[128 + t], b);
    }
}

// ---------------- fused subgraph pooling + MLP head ----------------

__global__ __launch_bounds__(256) void k_head(const __half* __restrict__ agg,
                                              const int* __restrict__ subg,
                                              const float* __restrict__ mW1,
                                              const float* __restrict__ mb1,
                                              const float* __restrict__ mW2,
                                              const float* __restrict__ mb2,
                                              float* __restrict__ out) {
    __shared__ int   idx[64];
    __shared__ float pl[4][64];
    __shared__ float red[128];
    int s = blockIdx.x, t = threadIdx.x;
    if (t < 64) idx[t] = subg[s * 64 + t];
    __syncthreads();
    int j = t & 63, grp = t >> 6;
    float acc = 0.f;
    #pragma unroll
    for (int m = grp * 16; m < grp * 16 + 16; m++) {
        int n = idx[m];
        acc += __half2float(agg[(size_t)n * 128 + j]) +
               __half2float(agg[(size_t)n * 128 + 64 + j]);
    }
    pl[grp][j] = acc * 0.5f;
    __syncthreads();
    if (t < 64) pl[0][t] = pl[0][t] + pl[1][t] + pl[2][t] + pl[3][t];
    __syncthreads();
    if (t < 128) {
        float h = mb1[t];
        #pragma unroll
        for (int k = 0; k < 64; k++) h += pl[0][k] * mW1[k * 128 + t];
        h = fmaxf(h, 0.0f);
        red[t] = h * mW2[t];
    }
    __syncthreads();
    for (int off = 64; off > 0; off >>= 1) {
        if (t < off) red[t] += red[t + off];
        __syncthreads();
    }
    if (t == 0) out[s] = red[0] + mb2[0];
}

// ---------------- launcher ----------------

extern "C" void kernel_launch(void* const* d_in, const int* in_sizes, int n_in,
                              void* d_out, int out_size, void* d_ws, size_t ws_size,
                              hipStream_t stream) {
    const float* x     = (const float*)d_in[0];
    const int*   ei    = (const int*)d_in[1];
    const float* ew    = (const float*)d_in[2];
    const int*   subg  = (const int*)d_in[3];
    const float* W1    = (const float*)d_in[4];
    const float* b1    = (const float*)d_in[5];
    const float* gn_w  = (const float*)d_in[6];
    const float* gn_b  = (const float*)d_in[7];
    const float* gn_ms = (const float*)d_in[8];
    const float* W2    = (const float*)d_in[9];
    const float* b2    = (const float*)d_in[10];
    const float* mW1   = (const float*)d_in[11];
    const float* mb1   = (const float*)d_in[12];
    const float* mW2   = (const float*)d_in[13];
    const float* mb2   = (const float*)d_in[14];
    float* out = (float*)d_out;

    char* w = (char*)d_ws;
    size_t off = 0;
    auto alloc = [&](size_t bytes) {
        void* p = w + off;
        off = (off + bytes + 255) & ~(size_t)255;
        return p;
    };
    float*    dinv    = (float*)   alloc((size_t)NNODES * 4);
    int*      cnt     = (int*)     alloc((size_t)NNODES * 4);
    int*      row_ptr = (int*)     alloc((size_t)NNODES * 4);
    int*      flags   = (int*)     alloc((size_t)NNODES * 4);
    unsigned* edges   = (unsigned*)alloc(((size_t)NEDGES + 16) * 4);  // +guard
    int2*     esw     = (int2*)    alloc((size_t)NEDGES * 8);
    __half*   hw      = (__half*)  alloc((size_t)NNODES * 128 * 2);
    __half*   agg     = (__half*)  alloc((size_t)NNODES * 128 * 2);
    float*    stats   = (float*)   alloc(512 * 4);
    int*      block_counts = (int*)alloc((size_t)NBLK * NWIN * 4);
    int*      block_off    = (int*)alloc((size_t)NBLK * NWIN * 4);
    int*      win_base     = (int*)alloc(NWIN * 4);
    int*      win_lim      = (int*)alloc(NWIN * 4);
    int*      cursor       = (int*)alloc(256);

    const int* src = ei;
    const int* dst = ei + NEDGES;

    // edge binning (counting sort by 512-node dst window) -> packed CSR + dinv
    k_hist   <<<NBLK, 256, 0, stream>>>(dst, block_counts, cursor, subg, flags);
    k_off    <<<NWIN, 256, 0, stream>>>(block_counts, cursor, win_base, win_lim,
                                        block_off, stats, edges);
    k_scatter<<<NBLK, 256, 0, stream>>>(src, dst, ew, block_off, esw);
    k_fill2  <<<NWIN, 256, 0, stream>>>(win_base, win_lim, esw, edges, row_ptr, cnt, dinv);

    // layer 1
    k_gemm<false><<<3125, 256, 0, stream>>>(x, W1, dinv, (_Float16*)hw,
                                            nullptr, nullptr, nullptr, nullptr);
    k_prop<false><<<25000, 256, 0, stream>>>(hw, b1, dinv, row_ptr, cnt, edges,
                                             nullptr, agg);

    // GraphNorm stats
    k_stats<<<512, 256, 0, stream>>>(agg, stats);

    // layer 2 (GraphNorm coef + affine + ReLU fused into GEMM2)
    k_gemm<true><<<3125, 256, 0, stream>>>(agg, W2, dinv, (_Float16*)hw,
                                           stats, gn_w, gn_b, gn_ms);
    k_prop<true><<<25000, 256, 0, stream>>>(hw, b2, dinv, row_ptr, cnt, edges,
                                            flags, agg);

    // fused pooling + MLP head
    k_head<<<NSUB, 256, 0, stream>>>(agg, subg, mW1, mb1, mW2, mb2, out);
}